// Round 5
// baseline (261.570 us; speedup 1.0000x reference)
//
#include <hip/hip_runtime.h>
#include <math.h>

// Problem constants (from reference)
#define BB   2
#define LQ   24
#define LK   24
#define NH   4
#define DM   32     // d_model
#define DF   32     // d_feat
#define HW   256    // 16x16
#define NEG  0.1f

// Padded LDS image: 20 rows, pitch 24 floats -> 2-way bank aliasing (free).
#define PITCH 24
#define CHPAD (20 * PITCH)   // 480 floats per channel image

#define NIMG  (BB * NH * LK)  // 192 head-images
#define NBLK  (NIMG * 4)      // 768 blocks = 3/CU exactly
#define MAGIC 0x13579BDFu
#define SPIN_CAP (1 << 22)

__device__ __forceinline__ float lrelu(float x) { return x >= 0.f ? x : NEG * x; }

// Hand-rolled grid barrier pieces (coop launch failed in this harness, R4).
// bar[0]=init flag, bar[32]=counter A->B, bar[64]=counter B->C (separate lines).
__device__ __forceinline__ void bar_wait(unsigned* cnt) {
    __threadfence();                      // release prior global writes
    atomicAdd(cnt, 1u);                   // device-scope (m20)
    int g = 0;
    while (__hip_atomic_load(cnt, __ATOMIC_RELAXED, __HIP_MEMORY_SCOPE_AGENT)
               < (unsigned)NBLK && g < SPIN_CAP) {
        __builtin_amdgcn_s_sleep(2); ++g;
    }
    __threadfence();                      // acquire other blocks' writes
}

// -----------------------------------------------------------------------------
// Fused kernel, plain launch: 768 blocks x 256 threads, co-resident (3/CU,
// enforced by __launch_bounds__(256,3): LDS 15.4KB, VGPR<=170 -> capacity>=3).
// Phase A (768): per (img, 8-ch slice): V-proj -> vh, K-proj -> padded LDS,
//   5x5 conv partial -> ck4.  (q-side conv + b_attn cancel in softmax over keys)
// [grid barrier]
// Phase B (448): per-pixel softmax over j from 4 partials; u<24: attn slice for
//   query i=u (identical for all i); u>=24: res channel c=u-24.
// [grid barrier]
// Phase C (256): out = w_fc . res, broadcast over l (6 l's per block).
// -----------------------------------------------------------------------------
__global__ __launch_bounds__(256, 3) void k_fused(
    const float* __restrict__ kin, const float* __restrict__ vin,
    const float* __restrict__ wk, const float* __restrict__ bk,
    const float* __restrict__ wv, const float* __restrict__ bv,
    const float* __restrict__ wat, const float* __restrict__ wfc,
    float* __restrict__ vh, float* __restrict__ ck4,
    float* __restrict__ res, float* __restrict__ out,
    float* __restrict__ attn_out, unsigned* __restrict__ bar)
{
    const int bx = blockIdx.x;
    const int hw = threadIdx.x;

    // ws is poisoned 0xAA before every launch: block 0 zeroes the counters and
    // publishes MAGIC; everyone else waits for MAGIC before first atomicAdd.
    if (bx == 0 && hw == 0) {
        __hip_atomic_store(&bar[32], 0u, __ATOMIC_RELAXED, __HIP_MEMORY_SCOPE_AGENT);
        __hip_atomic_store(&bar[64], 0u, __ATOMIC_RELAXED, __HIP_MEMORY_SCOPE_AGENT);
        __threadfence();
        __hip_atomic_store(&bar[0], MAGIC, __ATOMIC_RELEASE, __HIP_MEMORY_SCOPE_AGENT);
    }

    __shared__ float skh[8][CHPAD];

    // ================= Phase A: projections + conv partial =================
    {
        const int img = bx >> 2;           // (b*NH + n)*LK + j
        const int cg_ = bx & 3;            // channel group: 8 channels
        const int b   = img / (NH * LK);
        const int n   = (img / LK) % NH;
        const int j   = img % LK;
        const int h   = hw >> 4, w = hw & 15;

        for (int idx = hw; idx < 8 * CHPAD; idx += 256) ((float*)skh)[idx] = 0.f;

        const float* kb = kin + (size_t)((b * LK + j) * DF) * HW + hw;
        const float* vb = vin + (size_t)((b * LK + j) * DF) * HW + hw;

        float xr[DF];

        // V projection: 8 out-channels of this group
        #pragma unroll
        for (int c = 0; c < DF; c++) xr[c] = vb[c * HW];
        #pragma unroll
        for (int d = 0; d < 8; d++) {
            const int o = n * DM + cg_ * 8 + d;
            const float* wr = wv + o * DF;
            float acc = bv[o];
            #pragma unroll
            for (int c = 0; c < DF; c++) acc += xr[c] * wr[c];
            vh[(size_t)img * (DM * HW) + (cg_ * 8 + d) * HW + hw] = lrelu(acc);
        }

        // K projection into padded LDS
        #pragma unroll
        for (int c = 0; c < DF; c++) xr[c] = kb[c * HW];
        __syncthreads();   // zero-fill complete before interior writes
        #pragma unroll
        for (int d = 0; d < 8; d++) {
            const int o = n * DM + cg_ * 8 + d;
            const float* wr = wk + o * DF;
            float acc = bk[o];
            #pragma unroll
            for (int c = 0; c < DF; c++) acc += xr[c] * wr[c];
            skh[d][(h + 2) * PITCH + (w + 2)] = lrelu(acc);
        }
        __syncthreads();

        // 5x5 conv partial over 8 channels (padding baked into LDS)
        float acc = 0.f;
        #pragma unroll
        for (int lc = 0; lc < 8; lc++) {
            const float* wc = wat + (cg_ * 8 + lc) * 25;
            #pragma unroll
            for (int ky = 0; ky < 5; ky++) {
                const float* row = &skh[lc][(h + ky) * PITCH + w];
                #pragma unroll
                for (int kx = 0; kx < 5; kx++)
                    acc += row[kx] * wc[ky * 5 + kx];
            }
        }
        ck4[(size_t)(cg_ * NIMG + img) * HW + hw] = acc;
    }

    // ---- grid barrier A->B ----
    __syncthreads();
    if (hw == 0) {
        int g = 0;
        while (__hip_atomic_load(&bar[0], __ATOMIC_ACQUIRE, __HIP_MEMORY_SCOPE_AGENT)
                   != MAGIC && g < SPIN_CAP) { __builtin_amdgcn_s_sleep(2); ++g; }
        bar_wait(&bar[32]);
    }
    __syncthreads();

    // ================= Phase B: softmax -> attn + res =================
    if (bx < BB * NH * 56) {
        const int bn = bx / 56;   // 0..7
        const int u  = bx % 56;   // 0..55

        float e[LK];
        const float* c0 = ck4 + (size_t)(0 * NIMG + bn * LK) * HW + hw;
        const float* c1 = ck4 + (size_t)(1 * NIMG + bn * LK) * HW + hw;
        const float* c2 = ck4 + (size_t)(2 * NIMG + bn * LK) * HW + hw;
        const float* c3 = ck4 + (size_t)(3 * NIMG + bn * LK) * HW + hw;
        float m = -1e30f;
        #pragma unroll
        for (int jj = 0; jj < LK; jj++) {
            e[jj] = (c0[jj * HW] + c1[jj * HW]) + (c2[jj * HW] + c3[jj * HW]);
            m = fmaxf(m, e[jj]);
        }
        float s = 0.f;
        #pragma unroll
        for (int jj = 0; jj < LK; jj++) { e[jj] = __expf(e[jj] - m); s += e[jj]; }
        const float inv = 1.f / s;
        #pragma unroll
        for (int jj = 0; jj < LK; jj++) e[jj] *= inv;

        if (u < LQ) {
            // attn output for query i=u (identical for every i)
            float* ao = attn_out + (size_t)((bn * LQ + u) * LK) * HW + hw;
            #pragma unroll
            for (int jj = 0; jj < LK; jj++) ao[jj * HW] = e[jj];
        } else {
            // res channel c = u - 24
            const int c = u - LQ;
            const float* vp = vh + (size_t)(bn * LK) * (DM * HW) + c * HW + hw;
            float acc = 0.f;
            #pragma unroll
            for (int jj = 0; jj < LK; jj++) acc += e[jj] * vp[(size_t)jj * DM * HW];
            res[(bn * DM + c) * HW + hw] = acc;
        }
    }

    // ---- grid barrier B->C ----
    __syncthreads();
    if (hw == 0) bar_wait(&bar[64]);
    __syncthreads();

    // ================= Phase C: final FC, broadcast over l =================
    if (bx < BB * DM * 4) {
        const int b  = bx >> 7;
        const int o  = (bx >> 2) & 31;
        const int lg = bx & 3;

        const float* rp = res + (size_t)b * (NH * DM) * HW + hw;
        const float* wr = wfc + o * (NH * DM);
        float acc = 0.f;
        #pragma unroll
        for (int nc = 0; nc < NH * DM; nc++) acc += wr[nc] * rp[nc * HW];

        #pragma unroll
        for (int l = lg * 6; l < lg * 6 + 6; l++)
            out[(size_t)((b * LQ + l) * DM + o) * HW + hw] = acc;
    }
}

// -----------------------------------------------------------------------------
extern "C" void kernel_launch(void* const* d_in, const int* in_sizes, int n_in,
                              void* d_out, int out_size, void* d_ws, size_t ws_size,
                              hipStream_t stream)
{
    // setup_inputs order: q,k,v,wq,bq,wk,bk,wv,bv,w_attn,b_attn,w_fc
    const float* k_in = (const float*)d_in[1];
    const float* v_in = (const float*)d_in[2];
    const float* wk   = (const float*)d_in[5];
    const float* bk   = (const float*)d_in[6];
    const float* wv   = (const float*)d_in[7];
    const float* bv   = (const float*)d_in[8];
    const float* wat  = (const float*)d_in[9];
    const float* wfc  = (const float*)d_in[11];
    // q, wq, bq, b_attn are provably unused (cancel in softmax over keys).

    float* out  = (float*)d_out;                       // (B,LQ,DM,H,W)
    float* attn = out + (size_t)BB * LQ * DM * HW;     // (B,NH,LQ,LK,1,H,W)

    float* vh  = (float*)d_ws;                                   // 1,572,864 f
    float* ck4 = vh  + (size_t)BB * NH * LK * DM * HW;           //   196,608 f
    float* res = ck4 + (size_t)4 * NIMG * HW;                    //    65,536 f
    unsigned* bar = (unsigned*)(res + (size_t)BB * NH * DM * HW);// 96 u32
    // total ws use: ~7.3 MB

    hipLaunchKernelGGL(k_fused, dim3(NBLK), dim3(256), 0, stream,
                       k_in, v_in, wk, bk, wv, bv, wat, wfc,
                       vh, ck4, res, out, attn, bar);
}

// Round 8
// 117.195 us; speedup vs baseline: 2.2319x; 2.2319x over previous
//
#include <hip/hip_runtime.h>
#include <math.h>

// Problem constants (from reference)
#define BB   2
#define LQ   24
#define LK   24
#define NH   4
#define DM   32     // d_model
#define DF   32     // d_feat
#define HW   256    // 16x16
#define NEG  0.1f

// Padded LDS image: 20 rows, pitch 24 floats. 2-way bank aliasing only (free;
// R1 vs R5 counter comparison shows SQ_LDS_BANK_CONFLICT just counts the
// inherent wave64/32-bank 2-pass, ~2.08/ds_read — not a real conflict).
#define PITCH 24
#define CHPAD (20 * PITCH)   // 480 floats per channel image

#define NIMG (BB * NH * LK)  // 192 head-images
#define NCG  8               // K1 channel-group split (4 channels each)

__device__ __forceinline__ float lrelu(float x) { return x >= 0.f ? x : NEG * x; }

// -----------------------------------------------------------------------------
// K1: grid 1536 = img * 8 + cg, 256 threads (1 thread/pixel).
// Each block: 4-channel slice of one head-image.
//  - project 4 V out-channels -> vh (global)
//  - project 4 K out-channels -> zero-padded LDS
//  - 5x5 conv partial over those 4 channels -> ck8[cg]
// R1->R2 showed K1 is latency-bound (4x split gave >4x). This halves the
// serial LDS chain again (200->100 reads). Natural occupancy: VGPR=68 ->
// 7 waves/SIMD; LDS 7.68KB -> 20 blocks/CU; so ~6 blocks/CU WITHOUT any
// launch-bounds floor (the (256,6) hint is untested on this harness and was
// in both container-crash rounds — removed to de-risk).
// -----------------------------------------------------------------------------
__global__ __launch_bounds__(256) void k_proj_conv(
    const float* __restrict__ kin, const float* __restrict__ vin,
    const float* __restrict__ wk, const float* __restrict__ bk,
    const float* __restrict__ wv, const float* __restrict__ bv,
    const float* __restrict__ wat,
    float* __restrict__ vh, float* __restrict__ ck8)
{
    const int bx  = blockIdx.x;
    const int img = bx >> 3;           // (b*NH + n)*LK + j
    const int cg  = bx & 7;            // channel group: 4 channels
    const int b   = img / (NH * LK);
    const int n   = (img / LK) % NH;
    const int j   = img % LK;
    const int hw  = threadIdx.x;
    const int h   = hw >> 4, w = hw & 15;

    __shared__ float skh[4][CHPAD];    // 7.68 KB

    for (int idx = hw; idx < 4 * CHPAD; idx += 256) ((float*)skh)[idx] = 0.f;

    const float* kb = kin + (size_t)((b * LK + j) * DF) * HW + hw;
    const float* vb = vin + (size_t)((b * LK + j) * DF) * HW + hw;

    float xr[DF];

    // ---- V projection: 4 out-channels of this group ----
    #pragma unroll
    for (int c = 0; c < DF; c++) xr[c] = vb[c * HW];
    #pragma unroll
    for (int d = 0; d < 4; d++) {
        const int o = n * DM + cg * 4 + d;
        const float* wr = wv + o * DF;
        float acc = bv[o];
        #pragma unroll
        for (int c = 0; c < DF; c++) acc += xr[c] * wr[c];
        vh[(size_t)img * (DM * HW) + (cg * 4 + d) * HW + hw] = lrelu(acc);
    }

    // ---- K projection into padded LDS ----
    #pragma unroll
    for (int c = 0; c < DF; c++) xr[c] = kb[c * HW];
    __syncthreads();   // zero-fill complete before interior writes
    #pragma unroll
    for (int d = 0; d < 4; d++) {
        const int o = n * DM + cg * 4 + d;
        const float* wr = wk + o * DF;
        float acc = bk[o];
        #pragma unroll
        for (int c = 0; c < DF; c++) acc += xr[c] * wr[c];
        skh[d][(h + 2) * PITCH + (w + 2)] = lrelu(acc);
    }
    __syncthreads();

    // ---- 5x5 conv partial over 4 channels (padding baked into LDS) ----
    float acc = 0.f;
    #pragma unroll
    for (int lc = 0; lc < 4; lc++) {
        const float* wc = wat + (cg * 4 + lc) * 25;
        #pragma unroll
        for (int ky = 0; ky < 5; ky++) {
            const float* row = &skh[lc][(h + ky) * PITCH + w];
            #pragma unroll
            for (int kx = 0; kx < 5; kx++)
                acc += row[kx] * wc[ky * 5 + kx];
        }
    }
    ck8[(size_t)(cg * NIMG + img) * HW + hw] = acc;
}

// -----------------------------------------------------------------------------
// K2: grid 448 = (bn = b*NH+n) * 56 + u, 256 threads (1 thread/pixel).
//  - per-pixel softmax over j (24) from the 8 conv partials, in registers
//    (q-side conv + b_attn cancel in the softmax over keys)
//  - u <  24: write attn slice for query i=u (identical for all i)
//  - u >= 24: res channel c=u-24 = sum_j A[j] * vh[j,c]
// -----------------------------------------------------------------------------
__global__ __launch_bounds__(256) void k_softmax_res(
    const float* __restrict__ ck8, const float* __restrict__ vh,
    float* __restrict__ res, float* __restrict__ attn_out)
{
    const int bn = blockIdx.x / 56;   // 0..7
    const int u  = blockIdx.x % 56;   // 0..55
    const int hw = threadIdx.x;

    float e[LK];
    const float* cbase = ck8 + (size_t)(bn * LK) * HW + hw;
    float m = -1e30f;
    #pragma unroll
    for (int jj = 0; jj < LK; jj++) {
        float s0 = 0.f, s1 = 0.f;
        #pragma unroll
        for (int g = 0; g < NCG; g += 2) {
            s0 += cbase[((size_t)g       * NIMG + jj) * HW];
            s1 += cbase[((size_t)(g + 1) * NIMG + jj) * HW];
        }
        e[jj] = s0 + s1;
        m = fmaxf(m, e[jj]);
    }
    float s = 0.f;
    #pragma unroll
    for (int jj = 0; jj < LK; jj++) { e[jj] = __expf(e[jj] - m); s += e[jj]; }
    const float inv = 1.f / s;
    #pragma unroll
    for (int jj = 0; jj < LK; jj++) e[jj] *= inv;

    if (u < LQ) {
        // attn output for query i=u (identical for every i)
        float* ao = attn_out + (size_t)((bn * LQ + u) * LK) * HW + hw;
        #pragma unroll
        for (int jj = 0; jj < LK; jj++) ao[jj * HW] = e[jj];
    } else {
        // res channel c = u - 24
        const int c = u - LQ;
        const float* vp = vh + (size_t)(bn * LK) * (DM * HW) + c * HW + hw;
        float acc = 0.f;
        #pragma unroll
        for (int jj = 0; jj < LK; jj++) acc += e[jj] * vp[(size_t)jj * DM * HW];
        res[(bn * DM + c) * HW + hw] = acc;
    }
}

// -----------------------------------------------------------------------------
// K3: final FC (128 -> 32), broadcast over l. grid 256 = b*128 + o*4 + lg,
// each block stores 6 of the 24 identical l-slices.
// -----------------------------------------------------------------------------
__global__ __launch_bounds__(256) void k_fc(
    const float* __restrict__ res, const float* __restrict__ wfc,
    float* __restrict__ out)
{
    const int bx = blockIdx.x;
    const int b  = bx >> 7;
    const int o  = (bx >> 2) & 31;
    const int lg = bx & 3;
    const int hw = threadIdx.x;

    const float* rp = res + (size_t)b * (NH * DM) * HW + hw;
    const float* wr = wfc + o * (NH * DM);
    float acc = 0.f;
    #pragma unroll
    for (int nc = 0; nc < NH * DM; nc++) acc += wr[nc] * rp[nc * HW];

    #pragma unroll
    for (int l = lg * 6; l < lg * 6 + 6; l++)
        out[(size_t)((b * LQ + l) * DM + o) * HW + hw] = acc;
}

// -----------------------------------------------------------------------------
extern "C" void kernel_launch(void* const* d_in, const int* in_sizes, int n_in,
                              void* d_out, int out_size, void* d_ws, size_t ws_size,
                              hipStream_t stream)
{
    // setup_inputs order: q,k,v,wq,bq,wk,bk,wv,bv,w_attn,b_attn,w_fc
    const float* k_in = (const float*)d_in[1];
    const float* v_in = (const float*)d_in[2];
    const float* wk   = (const float*)d_in[5];
    const float* bk   = (const float*)d_in[6];
    const float* wv   = (const float*)d_in[7];
    const float* bv   = (const float*)d_in[8];
    const float* wat  = (const float*)d_in[9];
    const float* wfc  = (const float*)d_in[11];
    // q, wq, bq, b_attn are provably unused (cancel in softmax over keys).

    float* out  = (float*)d_out;                       // (B,LQ,DM,H,W)
    float* attn = out + (size_t)BB * LQ * DM * HW;     // (B,NH,LQ,LK,1,H,W)

    float* vh  = (float*)d_ws;                                   // 1,572,864 f
    float* ck8 = vh  + (size_t)BB * NH * LK * DM * HW;           //   393,216 f
    float* res = ck8 + (size_t)NCG * NIMG * HW;                  //    65,536 f
    // total ws use: ~8.1 MB

    hipLaunchKernelGGL(k_proj_conv, dim3(NIMG * NCG), dim3(256), 0, stream,
                       k_in, v_in, wk, bk, wv, bv, wat, vh, ck8);
    hipLaunchKernelGGL(k_softmax_res, dim3(BB * NH * 56), dim3(256), 0, stream,
                       ck8, vh, res, attn);
    hipLaunchKernelGGL(k_fc, dim3(BB * DM * 4), dim3(256), 0, stream,
                       res, wfc, out);
}

// Round 9
// 101.247 us; speedup vs baseline: 2.5835x; 1.1575x over previous
//
#include <hip/hip_runtime.h>
#include <math.h>

// Problem constants (from reference)
#define BB   2
#define LQ   24
#define LK   24
#define NH   4
#define DM   32     // d_model
#define DF   32     // d_feat
#define HW   256    // 16x16
#define NEG  0.1f

// Padded LDS image: 20 rows, pitch 24 floats -> 2-way bank aliasing (free).
#define PITCH 24
#define CHPAD (20 * PITCH)   // 480 floats per channel image

#define NIMG (BB * NH * LK)  // 192 head-images

__device__ __forceinline__ float lrelu(float x) { return x >= 0.f ? x : NEG * x; }

// -----------------------------------------------------------------------------
// K1: grid 768 = img * 4 + cg, 256 threads (1 thread/pixel). [R3 structure:
// the verified best. R8's 8-way split regressed: doubled K/V input re-reads
// (49->98 MB L2 traffic) outweighed the halved serial conv chain.]
// Each block: 8-channel slice of one head-image.
//  - project 8 V out-channels -> vh (global)
//  - project 8 K out-channels -> zero-padded LDS
//  - 5x5 conv partial over those 8 channels -> plain store to ck4[cg]
// -----------------------------------------------------------------------------
__global__ __launch_bounds__(256) void k_proj_conv(
    const float* __restrict__ kin, const float* __restrict__ vin,
    const float* __restrict__ wk, const float* __restrict__ bk,
    const float* __restrict__ wv, const float* __restrict__ bv,
    const float* __restrict__ wat,
    float* __restrict__ vh, float* __restrict__ ck4)
{
    const int bx  = blockIdx.x;
    const int img = bx >> 2;           // (b*NH + n)*LK + j
    const int cg  = bx & 3;            // channel group: 8 channels
    const int b   = img / (NH * LK);
    const int n   = (img / LK) % NH;
    const int j   = img % LK;
    const int hw  = threadIdx.x;
    const int h   = hw >> 4, w = hw & 15;

    __shared__ float skh[8][CHPAD];

    for (int idx = hw; idx < 8 * CHPAD; idx += 256) ((float*)skh)[idx] = 0.f;

    const float* kb = kin + (size_t)((b * LK + j) * DF) * HW + hw;
    const float* vb = vin + (size_t)((b * LK + j) * DF) * HW + hw;

    float xr[DF];

    // ---- V projection: 8 out-channels of this group ----
    #pragma unroll
    for (int c = 0; c < DF; c++) xr[c] = vb[c * HW];
    #pragma unroll
    for (int d = 0; d < 8; d++) {
        const int o = n * DM + cg * 8 + d;
        const float* wr = wv + o * DF;
        float acc = bv[o];
        #pragma unroll
        for (int c = 0; c < DF; c++) acc += xr[c] * wr[c];
        vh[(size_t)img * (DM * HW) + (cg * 8 + d) * HW + hw] = lrelu(acc);
    }

    // ---- K projection into padded LDS ----
    #pragma unroll
    for (int c = 0; c < DF; c++) xr[c] = kb[c * HW];
    __syncthreads();   // zero-fill complete before interior writes
    #pragma unroll
    for (int d = 0; d < 8; d++) {
        const int o = n * DM + cg * 8 + d;
        const float* wr = wk + o * DF;
        float acc = bk[o];
        #pragma unroll
        for (int c = 0; c < DF; c++) acc += xr[c] * wr[c];
        skh[d][(h + 2) * PITCH + (w + 2)] = lrelu(acc);
    }
    __syncthreads();

    // ---- 5x5 conv partial over 8 channels (padding baked into LDS) ----
    float acc = 0.f;
    #pragma unroll
    for (int lc = 0; lc < 8; lc++) {
        const float* wc = wat + (cg * 8 + lc) * 25;
        #pragma unroll
        for (int ky = 0; ky < 5; ky++) {
            const float* row = &skh[lc][(h + ky) * PITCH + w];
            #pragma unroll
            for (int kx = 0; kx < 5; kx++)
                acc += row[kx] * wc[ky * 5 + kx];
        }
    }
    ck4[(size_t)(cg * NIMG + img) * HW + hw] = acc;
}

// -----------------------------------------------------------------------------
// K2: grid 448 = (bn = b*NH+n) * 56 + u, 256 threads (1 thread/pixel).
//  - per-pixel softmax over j (24) from the 4 conv partials, in registers
//    (q-side conv + b_attn cancel in the softmax over keys)
//  - u <  24: write attn slice for query i=u (identical for all i)
//  - u >= 24: res channel c=u-24 = sum_j A[j] * vh[j,c]
// -----------------------------------------------------------------------------
__global__ __launch_bounds__(256) void k_softmax_res(
    const float* __restrict__ ck4, const float* __restrict__ vh,
    float* __restrict__ res, float* __restrict__ attn_out)
{
    const int bn = blockIdx.x / 56;   // 0..7
    const int u  = blockIdx.x % 56;   // 0..55
    const int hw = threadIdx.x;

    float e[LK];
    const float* c0 = ck4 + (size_t)(0 * NIMG + bn * LK) * HW + hw;
    const float* c1 = ck4 + (size_t)(1 * NIMG + bn * LK) * HW + hw;
    const float* c2 = ck4 + (size_t)(2 * NIMG + bn * LK) * HW + hw;
    const float* c3 = ck4 + (size_t)(3 * NIMG + bn * LK) * HW + hw;
    float m = -1e30f;
    #pragma unroll
    for (int jj = 0; jj < LK; jj++) {
        e[jj] = (c0[jj * HW] + c1[jj * HW]) + (c2[jj * HW] + c3[jj * HW]);
        m = fmaxf(m, e[jj]);
    }
    float s = 0.f;
    #pragma unroll
    for (int jj = 0; jj < LK; jj++) { e[jj] = __expf(e[jj] - m); s += e[jj]; }
    const float inv = 1.f / s;
    #pragma unroll
    for (int jj = 0; jj < LK; jj++) e[jj] *= inv;

    if (u < LQ) {
        // attn output for query i=u (identical for every i)
        float* ao = attn_out + (size_t)((bn * LQ + u) * LK) * HW + hw;
        #pragma unroll
        for (int jj = 0; jj < LK; jj++) ao[jj * HW] = e[jj];
    } else {
        // res channel c = u - 24
        const int c = u - LQ;
        const float* vp = vh + (size_t)(bn * LK) * (DM * HW) + c * HW + hw;
        float acc = 0.f;
        #pragma unroll
        for (int jj = 0; jj < LK; jj++) acc += e[jj] * vp[(size_t)jj * DM * HW];
        res[(bn * DM + c) * HW + hw] = acc;
    }
}

// -----------------------------------------------------------------------------
// K3: final FC (128 -> 32), broadcast over l. grid 256 = b*128 + o*4 + lg,
// each block stores 6 of the 24 identical l-slices.
// -----------------------------------------------------------------------------
__global__ __launch_bounds__(256) void k_fc(
    const float* __restrict__ res, const float* __restrict__ wfc,
    float* __restrict__ out)
{
    const int bx = blockIdx.x;
    const int b  = bx >> 7;
    const int o  = (bx >> 2) & 31;
    const int lg = bx & 3;
    const int hw = threadIdx.x;

    const float* rp = res + (size_t)b * (NH * DM) * HW + hw;
    const float* wr = wfc + o * (NH * DM);
    float acc = 0.f;
    #pragma unroll
    for (int nc = 0; nc < NH * DM; nc++) acc += wr[nc] * rp[nc * HW];

    #pragma unroll
    for (int l = lg * 6; l < lg * 6 + 6; l++)
        out[(size_t)((b * LQ + l) * DM + o) * HW + hw] = acc;
}

// -----------------------------------------------------------------------------
extern "C" void kernel_launch(void* const* d_in, const int* in_sizes, int n_in,
                              void* d_out, int out_size, void* d_ws, size_t ws_size,
                              hipStream_t stream)
{
    // setup_inputs order: q,k,v,wq,bq,wk,bk,wv,bv,w_attn,b_attn,w_fc
    const float* k_in = (const float*)d_in[1];
    const float* v_in = (const float*)d_in[2];
    const float* wk   = (const float*)d_in[5];
    const float* bk   = (const float*)d_in[6];
    const float* wv   = (const float*)d_in[7];
    const float* bv   = (const float*)d_in[8];
    const float* wat  = (const float*)d_in[9];
    const float* wfc  = (const float*)d_in[11];
    // q, wq, bq, b_attn are provably unused (cancel in softmax over keys).

    float* out  = (float*)d_out;                       // (B,LQ,DM,H,W)
    float* attn = out + (size_t)BB * LQ * DM * HW;     // (B,NH,LQ,LK,1,H,W)

    float* vh  = (float*)d_ws;                                   // 1,572,864 f
    float* ck4 = vh  + (size_t)BB * NH * LK * DM * HW;           //   196,608 f
    float* res = ck4 + (size_t)4 * NIMG * HW;                    //    65,536 f
    // total ws use: ~7.3 MB

    hipLaunchKernelGGL(k_proj_conv, dim3(NIMG * 4), dim3(256), 0, stream,
                       k_in, v_in, wk, bk, wv, bv, wat, vh, ck4);
    hipLaunchKernelGGL(k_softmax_res, dim3(BB * NH * 56), dim3(256), 0, stream,
                       ck4, vh, res, attn);
    hipLaunchKernelGGL(k_fc, dim3(BB * DM * 4), dim3(256), 0, stream,
                       res, wfc, out);
}

// Round 13
// 101.217 us; speedup vs baseline: 2.5843x; 1.0003x over previous
//
#include <hip/hip_runtime.h>
#include <math.h>

// Problem constants (from reference)
#define BB   2
#define LQ   24
#define LK   24
#define NH   4
#define DM   32     // d_model
#define DF   32     // d_feat
#define HW   256    // 16x16
#define NEG  0.1f

// Padded LDS image: 20 rows, pitch 24 floats -> 2-way bank aliasing (free).
#define PITCH 24
#define CHPAD (20 * PITCH)   // 480 floats per channel image

#define NIMG (BB * NH * LK)  // 192 head-images

__device__ __forceinline__ float lrelu(float x) { return x >= 0.f ? x : NEG * x; }

// -----------------------------------------------------------------------------
// K1: grid 768 = img * 4 + cg, 256 threads (1 thread/pixel). [R3/R9 verified
// anchor source, resubmitted verbatim as an infra control after 3 consecutive
// container failures on R10/R11/R12.]
// Each block: 8-channel slice of one head-image.
//  - project 8 V out-channels -> vh (global)
//  - project 8 K out-channels -> zero-padded LDS
//  - 5x5 conv partial over those 8 channels -> plain store to ck4[cg]
// -----------------------------------------------------------------------------
__global__ __launch_bounds__(256) void k_proj_conv(
    const float* __restrict__ kin, const float* __restrict__ vin,
    const float* __restrict__ wk, const float* __restrict__ bk,
    const float* __restrict__ wv, const float* __restrict__ bv,
    const float* __restrict__ wat,
    float* __restrict__ vh, float* __restrict__ ck4)
{
    const int bx  = blockIdx.x;
    const int img = bx >> 2;           // (b*NH + n)*LK + j
    const int cg  = bx & 3;            // channel group: 8 channels
    const int b   = img / (NH * LK);
    const int n   = (img / LK) % NH;
    const int j   = img % LK;
    const int hw  = threadIdx.x;
    const int h   = hw >> 4, w = hw & 15;

    __shared__ float skh[8][CHPAD];

    for (int idx = hw; idx < 8 * CHPAD; idx += 256) ((float*)skh)[idx] = 0.f;

    const float* kb = kin + (size_t)((b * LK + j) * DF) * HW + hw;
    const float* vb = vin + (size_t)((b * LK + j) * DF) * HW + hw;

    float xr[DF];

    // ---- V projection: 8 out-channels of this group ----
    #pragma unroll
    for (int c = 0; c < DF; c++) xr[c] = vb[c * HW];
    #pragma unroll
    for (int d = 0; d < 8; d++) {
        const int o = n * DM + cg * 8 + d;
        const float* wr = wv + o * DF;
        float acc = bv[o];
        #pragma unroll
        for (int c = 0; c < DF; c++) acc += xr[c] * wr[c];
        vh[(size_t)img * (DM * HW) + (cg * 8 + d) * HW + hw] = lrelu(acc);
    }

    // ---- K projection into padded LDS ----
    #pragma unroll
    for (int c = 0; c < DF; c++) xr[c] = kb[c * HW];
    __syncthreads();   // zero-fill complete before interior writes
    #pragma unroll
    for (int d = 0; d < 8; d++) {
        const int o = n * DM + cg * 8 + d;
        const float* wr = wk + o * DF;
        float acc = bk[o];
        #pragma unroll
        for (int c = 0; c < DF; c++) acc += xr[c] * wr[c];
        skh[d][(h + 2) * PITCH + (w + 2)] = lrelu(acc);
    }
    __syncthreads();

    // ---- 5x5 conv partial over 8 channels (padding baked into LDS) ----
    float acc = 0.f;
    #pragma unroll
    for (int lc = 0; lc < 8; lc++) {
        const float* wc = wat + (cg * 8 + lc) * 25;
        #pragma unroll
        for (int ky = 0; ky < 5; ky++) {
            const float* row = &skh[lc][(h + ky) * PITCH + w];
            #pragma unroll
            for (int kx = 0; kx < 5; kx++)
                acc += row[kx] * wc[ky * 5 + kx];
        }
    }
    ck4[(size_t)(cg * NIMG + img) * HW + hw] = acc;
}

// -----------------------------------------------------------------------------
// K2: grid 448 = (bn = b*NH+n) * 56 + u, 256 threads (1 thread/pixel).
//  - per-pixel softmax over j (24) from the 4 conv partials, in registers
//    (q-side conv + b_attn cancel in the softmax over keys)
//  - u <  24: write attn slice for query i=u (identical for all i)
//  - u >= 24: res channel c=u-24 = sum_j A[j] * vh[j,c]
// -----------------------------------------------------------------------------
__global__ __launch_bounds__(256) void k_softmax_res(
    const float* __restrict__ ck4, const float* __restrict__ vh,
    float* __restrict__ res, float* __restrict__ attn_out)
{
    const int bn = blockIdx.x / 56;   // 0..7
    const int u  = blockIdx.x % 56;   // 0..55
    const int hw = threadIdx.x;

    float e[LK];
    const float* c0 = ck4 + (size_t)(0 * NIMG + bn * LK) * HW + hw;
    const float* c1 = ck4 + (size_t)(1 * NIMG + bn * LK) * HW + hw;
    const float* c2 = ck4 + (size_t)(2 * NIMG + bn * LK) * HW + hw;
    const float* c3 = ck4 + (size_t)(3 * NIMG + bn * LK) * HW + hw;
    float m = -1e30f;
    #pragma unroll
    for (int jj = 0; jj < LK; jj++) {
        e[jj] = (c0[jj * HW] + c1[jj * HW]) + (c2[jj * HW] + c3[jj * HW]);
        m = fmaxf(m, e[jj]);
    }
    float s = 0.f;
    #pragma unroll
    for (int jj = 0; jj < LK; jj++) { e[jj] = __expf(e[jj] - m); s += e[jj]; }
    const float inv = 1.f / s;
    #pragma unroll
    for (int jj = 0; jj < LK; jj++) e[jj] *= inv;

    if (u < LQ) {
        // attn output for query i=u (identical for every i)
        float* ao = attn_out + (size_t)((bn * LQ + u) * LK) * HW + hw;
        #pragma unroll
        for (int jj = 0; jj < LK; jj++) ao[jj * HW] = e[jj];
    } else {
        // res channel c = u - 24
        const int c = u - LQ;
        const float* vp = vh + (size_t)(bn * LK) * (DM * HW) + c * HW + hw;
        float acc = 0.f;
        #pragma unroll
        for (int jj = 0; jj < LK; jj++) acc += e[jj] * vp[(size_t)jj * DM * HW];
        res[(bn * DM + c) * HW + hw] = acc;
    }
}

// -----------------------------------------------------------------------------
// K3: final FC (128 -> 32), broadcast over l. grid 256 = b*128 + o*4 + lg,
// each block stores 6 of the 24 identical l-slices.
// -----------------------------------------------------------------------------
__global__ __launch_bounds__(256) void k_fc(
    const float* __restrict__ res, const float* __restrict__ wfc,
    float* __restrict__ out)
{
    const int bx = blockIdx.x;
    const int b  = bx >> 7;
    const int o  = (bx >> 2) & 31;
    const int lg = bx & 3;
    const int hw = threadIdx.x;

    const float* rp = res + (size_t)b * (NH * DM) * HW + hw;
    const float* wr = wfc + o * (NH * DM);
    float acc = 0.f;
    #pragma unroll
    for (int nc = 0; nc < NH * DM; nc++) acc += wr[nc] * rp[nc * HW];

    #pragma unroll
    for (int l = lg * 6; l < lg * 6 + 6; l++)
        out[(size_t)((b * LQ + l) * DM + o) * HW + hw] = acc;
}

// -----------------------------------------------------------------------------
extern "C" void kernel_launch(void* const* d_in, const int* in_sizes, int n_in,
                              void* d_out, int out_size, void* d_ws, size_t ws_size,
                              hipStream_t stream)
{
    // setup_inputs order: q,k,v,wq,bq,wk,bk,wv,bv,w_attn,b_attn,w_fc
    const float* k_in = (const float*)d_in[1];
    const float* v_in = (const float*)d_in[2];
    const float* wk   = (const float*)d_in[5];
    const float* bk   = (const float*)d_in[6];
    const float* wv   = (const float*)d_in[7];
    const float* bv   = (const float*)d_in[8];
    const float* wat  = (const float*)d_in[9];
    const float* wfc  = (const float*)d_in[11];
    // q, wq, bq, b_attn are provably unused (cancel in softmax over keys).

    float* out  = (float*)d_out;                       // (B,LQ,DM,H,W)
    float* attn = out + (size_t)BB * LQ * DM * HW;     // (B,NH,LQ,LK,1,H,W)

    float* vh  = (float*)d_ws;                                   // 1,572,864 f
    float* ck4 = vh  + (size_t)BB * NH * LK * DM * HW;           //   196,608 f
    float* res = ck4 + (size_t)4 * NIMG * HW;                    //    65,536 f
    // total ws use: ~7.3 MB

    hipLaunchKernelGGL(k_proj_conv, dim3(NIMG * 4), dim3(256), 0, stream,
                       k_in, v_in, wk, bk, wv, bv, wat, vh, ck4);
    hipLaunchKernelGGL(k_softmax_res, dim3(BB * NH * 56), dim3(256), 0, stream,
                       ck4, vh, res, attn);
    hipLaunchKernelGGL(k_fc, dim3(BB * DM * 4), dim3(256), 0, stream,
                       res, wfc, out);
}